// Round 15
// baseline (333.378 us; speedup 1.0000x reference)
//
#include <hip/hip_runtime.h>
#include <stdint.h>

// Problem constants
// B=8, R=40, L=128, IN=256, WDIM=512, DREL=15, F=200 (pad 256), HID=300

#define LK(x) ((x) > 0.f ? (x) : 0.01f*(x))

typedef __attribute__((ext_vector_type(8))) short s16x8;
typedef __attribute__((ext_vector_type(4))) float f32x4;
typedef unsigned long long ull;

__device__ __forceinline__ unsigned short f2bf(float f) {
  union { float f; unsigned int u; } v; v.f = f;
  unsigned int u = v.u;
  return (unsigned short)((u + 0x7FFFu + ((u >> 16) & 1u)) >> 16);
}

// HW packed f32->bf16 (RNE, matches f2bf for normal floats): low16=lo, high16=hi
__device__ __forceinline__ unsigned cvtpk(float lo, float hi) {
  unsigned r;
  asm("v_cvt_pk_bf16_f32 %0, %1, %2" : "=v"(r) : "v"(lo), "v"(hi));
  return r;
}

__device__ __forceinline__ void gload_lds16(const void* g, void* l) {
  __builtin_amdgcn_global_load_lds(
      (const __attribute__((address_space(1))) unsigned int*)g,
      (__attribute__((address_space(3))) unsigned int*)l, 16, 0, 0);
}

// ---------------- Kernel A: small preps --------------------------------
// bid <600: h dots (wave-per-output); 600..999: trans dots; 1000..1063:
// word_h->bf16; 1064..1127: arc_W->bf16 (paired cvt_pk); 1128: RW^T.
__global__ __launch_bounds__(256) void k_prep(
    const float* __restrict__ e1, const float* __restrict__ e2,
    const float* __restrict__ rel, const float* __restrict__ aW,
    const float* __restrict__ ffW, const float* __restrict__ ffb,
    const float* __restrict__ itW, const float* __restrict__ itb,
    const float* __restrict__ wh,
    unsigned short* __restrict__ whbf, unsigned short* __restrict__ aw1,
    unsigned short* __restrict__ aw2, unsigned short* __restrict__ rwt,
    float* __restrict__ hg, float* __restrict__ trans)
{
  int bid = blockIdx.x, t = threadIdx.x;
  if (bid < 1000) {
    int wv = t >> 6, l = t & 63;
    bool ish = bid < 600;
    int idx = ish ? bid*4 + wv : (bid - 600)*4 + wv;
    int ob = ish ? 300 : 200;
    int b = idx / ob, o = idx - b*ob;
    const float* W = ish ? ffW : itW;
    const float* bias = ish ? ffb : itb;
    const float4* wr = (const float4*)(W + (size_t)o*1024) + l*4;
    const float* inb = (l < 32) ? (e1 + b*512 + l*16)
                                : (e2 + b*512 + (l - 32)*16);
    float s = 0.f;
#pragma unroll
    for (int q = 0; q < 4; ++q) {
      float4 w = wr[q];
      float4 v = *(const float4*)(inb + q*4);
      s += w.x*v.x + w.y*v.y + w.z*v.z + w.w*v.w;
    }
#pragma unroll
    for (int sh = 1; sh < 64; sh <<= 1)
      s += __shfl_xor(s, sh);
    if (l == 0) {
      float r = LK(s + bias[o]);
      if (ish) hg[b*300 + o] = r; else trans[b*200 + o] = r;
    }
  } else if (bid < 1064) {
    int id0 = (bid - 1000)*256 + t;
    for (int v = id0; v < 131072; v += 64*256) {
      float4 x = ((const float4*)wh)[v];
      unsigned lo  = cvtpk(x.x, x.y);
      unsigned hi2 = cvtpk(x.z, x.w);
      *(ull*)(whbf + (size_t)v*4) = (ull)lo | ((ull)hi2 << 32);
    }
  } else if (bid < 1128) {
    int id0 = (bid - 1064)*256 + t;
    for (int p = id0; p < 65536; p += 64*256) {
      int e = p*2;
      int o = e >> 9, k = e & 511;          // k even <= 510, pair in-row
      const float* ra = aW + (size_t)o*1039 + k;
      *(unsigned*)(aw1 + e) = cvtpk(ra[0], ra[1]);
      const float* rb = aW + (size_t)o*1039 + 512 + k;
      *(unsigned*)(aw2 + e) = cvtpk(rb[0], rb[1]);
    }
  } else {
    int o = t;
    for (int r = 0; r < 40; ++r) {
      float s = 0.f;
      for (int d = 0; d < 15; ++d) s += rel[r*15 + d] * aW[(size_t)o*1039 + 1024 + d];
      rwt[o*72 + r] = f2bf(s);
    }
    for (int r = 40; r < 72; ++r) rwt[o*72 + r] = 0;
  }
}

// ---------------- Kernel B: P/Q GEMMs (MFMA) ---------------------------
__global__ __launch_bounds__(256) void k_pq(
    const unsigned short* __restrict__ whbf,
    const unsigned short* __restrict__ aw1,
    const unsigned short* __restrict__ aw2,
    float* __restrict__ Pg, float* __restrict__ Qg)
{
  int bid = blockIdx.x, t = threadIdx.x;
  int g = bid >> 8;
  int wv = t >> 6, l = t & 63, lm = l & 15, hi = l >> 4;
  int tile = (bid & 255)*4 + wv;
  int ot = tile & 15, nt = tile >> 4;
  const unsigned short* A = g ? aw2 : aw1;
  float* out = g ? Qg : Pg;
  int orow = ot*16 + lm, n = nt*16 + lm;
  f32x4 acc = {0.f, 0.f, 0.f, 0.f};
  const unsigned short* ap = A + (size_t)orow*512 + hi*8;
  const unsigned short* bp = whbf + (size_t)n*512 + hi*8;
#pragma unroll
  for (int kk = 0; kk < 16; ++kk) {
    s16x8 af = *(const s16x8*)(ap + kk*32);
    s16x8 bf = *(const s16x8*)(bp + kk*32);
    acc = __builtin_amdgcn_mfma_f32_16x16x32_bf16(bf, af, acc, 0, 0, 0);
  }
  int nb = nt*16 + hi*4, o = ot*16 + lm;
#pragma unroll
  for (int r = 0; r < 4; ++r)
    out[(size_t)(nb + r)*256 + o] = acc[r];
}

// ---------------- Fused kernel: filt (blocks 0..3599) + arc (3600..4623)
// filt FIRST: its 553-MB HBM stream starts at t=0; arc (VALU/write-heavy,
// 21 MB read) backfills. filt blocks now cover 128 rows (2 row-tiles per
// wave): per-block Bbuf staging + barrier + tail costs halved vs 64-row.
__global__ __launch_bounds__(256) void k_fa(
    const float* __restrict__ energy,
    const unsigned short* __restrict__ rwt,
    const float* __restrict__ Pg, const float* __restrict__ Qg,
    const float* __restrict__ arcb, unsigned short* __restrict__ memb,
    const float* __restrict__ fw1, const float* __restrict__ fb1,
    const float* __restrict__ hg, unsigned short* __restrict__ filtX)
{
  __shared__ __align__(16) char sm[21504];
  int bid = blockIdx.x, t = threadIdx.x;
  if (bid >= 3600) {
    // ---------------- arc body ----------------
    unsigned short* Et = (unsigned short*)sm;        // 18,432 B
    float* mpart = (float*)(sm + 18432);             //  1,024 B
    float* qlds  = (float*)(sm + 19456);             //  1,024 B
    float* blds  = (float*)(sm + 20480);             //  1,024 B
    int bid2 = bid - 3600;
    int b = bid2 >> 7, i = bid2 & 127;
    int jj = t & 127, half = t >> 7;
    float macc = 0.f;
    for (int rr = 0; rr < 20; rr += 2) {
      int r = half*20 + rr;                           // even -> 4-aligned
      float e0 = fmaxf(energy[(((size_t)b*40 + r  )*128 + i)*128 + jj], 0.f);
      float e1 = fmaxf(energy[(((size_t)b*40 + r+1)*128 + i)*128 + jj], 0.f);
      macc += e0;
      macc += e1;
      *(unsigned*)(Et + jj*72 + r) = cvtpk(e0, e1);
    }
    mpart[t] = macc;
    if (t < 128) {
#pragma unroll
      for (int r = 40; r < 72; ++r) Et[t*72 + r] = 0;
    }
    qlds[t] = Qg[((size_t)(b*128 + i))*256 + t];
    blds[t] = arcb[t];
    __syncthreads();

    int wv = t >> 6, l = t & 63, lm = l & 15, hi = l >> 4;
    unsigned short* mout = memb + ((size_t)(b*128 + i))*128*256;
    for (int otl = 0; otl < 4; ++otl) {
      int ocb = (wv*4 + otl)*16;
      const unsigned short* rp = rwt + (ocb + lm)*72 + hi*8;
      s16x8 rw0 = *(const s16x8*)rp;
      s16x8 rw1 = *(const s16x8*)(rp + 32);
      int oc0 = ocb + hi*4;
      float4 q4 = *(const float4*)&qlds[oc0];
      float4 b4 = *(const float4*)&blds[oc0];
      for (int jt = 0; jt < 8; ++jt) {
        const unsigned short* ep = &Et[(jt*16 + lm)*72 + hi*8];
        s16x8 et0 = *(const s16x8*)ep;
        s16x8 et1 = *(const s16x8*)(ep + 32);
        f32x4 acc = {0.f,0.f,0.f,0.f};
        acc = __builtin_amdgcn_mfma_f32_16x16x32_bf16(rw0, et0, acc, 0, 0, 0);
        acc = __builtin_amdgcn_mfma_f32_16x16x32_bf16(rw1, et1, acc, 0, 0, 0);
        int j = jt*16 + lm;
        float m = mpart[j] + mpart[128 + j];
        float4 p4 = *(const float4*)&Pg[((size_t)(b*128 + j))*256 + oc0];
        float vv0 = LK(acc[0] + m*(p4.x + q4.x) + b4.x);
        float vv1 = LK(acc[1] + m*(p4.y + q4.y) + b4.y);
        float vv2 = LK(acc[2] + m*(p4.z + q4.z) + b4.z);
        float vv3 = LK(acc[3] + m*(p4.w + q4.w) + b4.w);
        unsigned p0 = cvtpk(vv0, vv1), p1 = cvtpk(vv2, vv3);
        *(ull*)(mout + (size_t)j*256 + oc0) = (ull)p0 | ((ull)p1 << 32);
      }
    }
  } else {
    // ---------------- filt body: 128 rows per block ----------------
    unsigned short* Bbuf = (unsigned short*)sm;      // 10,240 B
    int r0 = bid*128;
    for (int idx = t; idx < 640; idx += 256) {
      int n = idx / 40, kc = idx - (idx/40)*40;
      unsigned w[4];
#pragma unroll
      for (int j = 0; j < 8; j += 2) {
        int k = kc*8 + j;
        float a = (n < 8 && k   < 300) ? hg[n*300 + k]     : 0.f;
        float b = (n < 8 && k+1 < 300) ? hg[n*300 + k + 1] : 0.f;
        w[j>>1] = cvtpk(a, b);
      }
      int byte = (n*640 + kc*16) ^ ((n & 7) << 4);
      *(uint4*)((char*)Bbuf + byte) = *(uint4*)w;
    }
    __syncthreads();
    int wv = t >> 6, l = t & 63, lm = l & 15, hi = l >> 4;
    const float* arow0 = fw1 + (size_t)(r0 + wv*32 + lm)*300;
    const float* arow1 = arow0 + 16*300;
    f32x4 acc0 = {0.f, 0.f, 0.f, 0.f};
    f32x4 acc1 = {0.f, 0.f, 0.f, 0.f};
#pragma unroll
    for (int ks = 0; ks < 10; ++ks) {
      int k0 = ks*32 + hi*8;
      float av0[8], av1[8];
      if (k0 + 8 <= 300) {
        float4 v0 = *(const float4*)(arow0 + k0);
        float4 v1 = *(const float4*)(arow0 + k0 + 4);
        float4 u0 = *(const float4*)(arow1 + k0);
        float4 u1 = *(const float4*)(arow1 + k0 + 4);
        av0[0]=v0.x; av0[1]=v0.y; av0[2]=v0.z; av0[3]=v0.w;
        av0[4]=v1.x; av0[5]=v1.y; av0[6]=v1.z; av0[7]=v1.w;
        av1[0]=u0.x; av1[1]=u0.y; av1[2]=u0.z; av1[3]=u0.w;
        av1[4]=u1.x; av1[5]=u1.y; av1[6]=u1.z; av1[7]=u1.w;
      } else {
#pragma unroll
        for (int e = 0; e < 8; ++e) {
          int k = k0 + e;
          av0[e] = (k < 300) ? arow0[k] : 0.f;
          av1[e] = (k < 300) ? arow1[k] : 0.f;
        }
      }
      union { s16x8 v; unsigned u[4]; } af0, af1;
      af0.u[0] = cvtpk(av0[0], av0[1]);
      af0.u[1] = cvtpk(av0[2], av0[3]);
      af0.u[2] = cvtpk(av0[4], av0[5]);
      af0.u[3] = cvtpk(av0[6], av0[7]);
      af1.u[0] = cvtpk(av1[0], av1[1]);
      af1.u[1] = cvtpk(av1[2], av1[3]);
      af1.u[2] = cvtpk(av1[4], av1[5]);
      af1.u[3] = cvtpk(av1[6], av1[7]);
      int bbyte = (lm*640 + ks*64 + hi*16) ^ ((lm & 7) << 4);
      s16x8 bf = *(const s16x8*)((char*)Bbuf + bbyte);
      acc0 = __builtin_amdgcn_mfma_f32_16x16x32_bf16(af0.v, bf, acc0, 0, 0, 0);
      acc1 = __builtin_amdgcn_mfma_f32_16x16x32_bf16(af1.v, bf, acc1, 0, 0, 0);
    }
    if (lm < 8) {
#pragma unroll
      for (int r = 0; r < 4; ++r) {
        int w0 = r0 + wv*32 + hi*4 + r;
        filtX[(size_t)w0*8 + lm] = f2bf(LK(acc0[r] + fb1[w0]));
        int w1 = w0 + 16;
        filtX[(size_t)w1*8 + lm] = f2bf(LK(acc1[r] + fb1[w1]));
      }
    }
  }
}

// ---------------- Kernel C2: transpose filtX -> filtg ------------------
__global__ __launch_bounds__(256) void k_tr(
    const unsigned short* __restrict__ filtX,
    unsigned short* __restrict__ filtg)
{
  __shared__ unsigned short sh[8*2312];  // 36,992 B
  int bid = blockIdx.x, t = threadIdx.x;
  int dc = bid >> 5, fch = bid & 31;
  if (fch >= 25) {
    uint4 z = {0,0,0,0};
#pragma unroll
    for (int i = 0; i < 9; ++i) {
      int idx = t + i*256;
      int b = idx / 288, rem = idx - b*288;
      char* dst = (char*)filtg + ((size_t)(b*8+dc)*256 + fch*8)*576 + rem*16;
      *(uint4*)dst = z;
    }
    return;
  }
#pragma unroll
  for (int i = 0; i < 9; ++i) {
    int rr = t + i*256;
    int f_loc = rr / 288, e = rr - f_loc*288;
    int dl = e / 9, tap = e - dl*9;
    size_t wrow = (size_t)(fch*8 + f_loc)*2304 + dc*288 + e;
    uint4 v = *(const uint4*)((const char*)filtX + wrow*16);
    const unsigned short* pv = (const unsigned short*)&v;
    int base = f_loc*288 + tap*32 + dl;
#pragma unroll
    for (int b = 0; b < 8; ++b)
      sh[b*2312 + base] = pv[b];
  }
  __syncthreads();
#pragma unroll
  for (int i = 0; i < 9; ++i) {
    int idx = t + i*256;
    int b = idx / 288, rem = idx - b*288;
    uint4 v = *(const uint4*)((const char*)sh + b*4624 + rem*16);
    char* dst = (char*)filtg + ((size_t)(b*8+dc)*256 + fch*8)*576 + rem*16;
    *(uint4*)dst = v;
  }
}

// ---------------- Kernel D: conv + fused leaky/maxpool -----------------
// (r8 structure, unchanged; dur ~113 us from r9 probe)
__global__ __launch_bounds__(256, 2) void k_conv(
    const unsigned short* __restrict__ filtg,
    const unsigned short* __restrict__ memb,
    float* __restrict__ part)
{
  __shared__ __align__(16) char smem[50688];   // 6 rows x 528 x 16 B
  int t = threadIdx.x;
  int bid = (blockIdx.x & 7)*128 + (blockIdx.x >> 3);
  int yq = bid & 31;
  int tmp = bid >> 5;
  int fc = tmp & 3, b = tmp >> 2;
  int y0 = yq*4;
  int wv = t >> 6, l = t & 63, lm = l & 15, hi = l >> 4;
  int wx = wv & 1, wf = wv >> 1;

  f32x4 zero = {0.f,0.f,0.f,0.f};
  f32x4 acc[4][4][2];
#pragma unroll
  for (int yb = 0; yb < 4; ++yb)
#pragma unroll
    for (int xt = 0; xt < 4; ++xt) { acc[yb][xt][0] = zero; acc[yb][xt][1] = zero; }

  const char* fb0 = (const char*)filtg +
      ((size_t)(b*8)*256 + fc*64 + wf*32 + lm)*576 + hi*16;

  for (int dc = 0; dc < 8; ++dc) {
    s16x8 freg[2][9];
    const char* fdc = fb0 + (size_t)dc*(256*576);
#pragma unroll
    for (int ft = 0; ft < 2; ++ft)
#pragma unroll
      for (int tap = 0; tap < 9; ++tap)
        freg[ft][tap] = *(const s16x8*)(fdc + ft*(16*576) + tap*64);
    for (int c = wv; c < 50; c += 4) {
      int id = c*64 + l;
      if (id < 3168) {
        int ky = id / 528;
        int rem = id - ky*528;
        int x = rem >> 2, s = rem & 3;
        int cs = s ^ ((x >> 1) & 3);
        int xs = (x < 128) ? x : 127;
        int row = y0 + ky; if (row > 127) row = 127;
        const char* ms = (const char*)memb +
            (((((size_t)(b*128 + row))*128 + xs)*256) + dc*32 + cs*8)*2;
        gload_lds16(ms, smem + c*1024);
      }
    }
    __syncthreads();
#pragma unroll
    for (int r = 0; r < 6; ++r) {
#pragma unroll
      for (int kx = 0; kx < 3; ++kx) {
#pragma unroll
        for (int xt = 0; xt < 4; ++xt) {
          int x = wx*64 + xt*16 + lm + kx;
          int slot = hi ^ ((x >> 1) & 3);
          s16x8 af = *(const s16x8*)(smem + ((r*132 + x)*4 + slot)*16);
#pragma unroll
          for (int yb = 0; yb < 4; ++yb) {
            const int ky = r - yb;
            if (ky >= 0 && ky <= 2) {
              acc[yb][xt][0] = __builtin_amdgcn_mfma_f32_16x16x32_bf16(af, freg[0][ky*3+kx], acc[yb][xt][0], 0,0,0);
              acc[yb][xt][1] = __builtin_amdgcn_mfma_f32_16x16x32_bf16(af, freg[1][ky*3+kx], acc[yb][xt][1], 0,0,0);
            }
          }
        }
      }
    }
    __syncthreads();
  }

  float pm[4][2];
#pragma unroll
  for (int yb = 0; yb < 4; ++yb) { pm[yb][0] = -3.4e38f; pm[yb][1] = -3.4e38f; }
#pragma unroll
  for (int yb = 0; yb < 4; ++yb)
#pragma unroll
    for (int xt = 0; xt < 4; ++xt) {
      int xb = wx*64 + xt*16 + hi*4;
#pragma unroll
      for (int r = 0; r < 4; ++r) {
        if (xb + r < 126) {
          pm[yb][0] = fmaxf(pm[yb][0], acc[yb][xt][0][r]);
          pm[yb][1] = fmaxf(pm[yb][1], acc[yb][xt][1][r]);
        }
      }
    }
#pragma unroll
  for (int yb = 0; yb < 4; ++yb)
#pragma unroll
    for (int ft = 0; ft < 2; ++ft) {
      pm[yb][ft] = fmaxf(pm[yb][ft], __shfl_xor(pm[yb][ft], 16));
      pm[yb][ft] = fmaxf(pm[yb][ft], __shfl_xor(pm[yb][ft], 32));
    }
  float* red = (float*)smem;
  if (l < 16) {
#pragma unroll
    for (int yb = 0; yb < 4; ++yb)
#pragma unroll
      for (int ft = 0; ft < 2; ++ft)
        red[(yb*4 + wf*2 + wx)*32 + ft*16 + lm] = pm[yb][ft];
  }
  __syncthreads();
  {
    int yb = t >> 6, tt = t & 63;
    int wfi = tt >> 5, fi = tt & 31;
    if (y0 + yb < 126) {
      float v = fmaxf(red[(yb*4 + wfi*2 + 0)*32 + fi], red[(yb*4 + wfi*2 + 1)*32 + fi]);
      v = LK(v);
      part[((size_t)(b*126 + y0 + yb))*256 + fc*64 + tt] = v;
    }
  }
}

// ---------------- Final: reduce over y, add transformed ----------------
__global__ __launch_bounds__(256) void k_final(
    const float* __restrict__ part, const float* __restrict__ trans,
    float* __restrict__ out)
{
  int bid = blockIdx.x, t = threadIdx.x;
  int b = bid >> 3, fg = bid & 7;
  int f = fg*32 + (t >> 3), ys = t & 7;
  float m = -3.4e38f;
  for (int yy = ys; yy < 126; yy += 8)
    m = fmaxf(m, part[((size_t)(b*126 + yy))*256 + f]);
  m = fmaxf(m, __shfl_xor(m, 1));
  m = fmaxf(m, __shfl_xor(m, 2));
  m = fmaxf(m, __shfl_xor(m, 4));
  if (ys == 0 && f < 200)
    out[b*200 + f] = trans[b*200 + f] + m;
}

extern "C" void kernel_launch(void* const* d_in, const int* in_sizes, int n_in,
                              void* d_out, int out_size, void* d_ws, size_t ws_size,
                              hipStream_t stream)
{
  (void)in_sizes; (void)n_in; (void)out_size; (void)ws_size;
  const float* energy = (const float*)d_in[0];
  const float* word_h = (const float*)d_in[1];
  const float* e1     = (const float*)d_in[2];
  const float* e2     = (const float*)d_in[3];
  // d_in[4] sent_len unused
  const float* rel    = (const float*)d_in[5];
  const float* aW     = (const float*)d_in[6];
  const float* arcb   = (const float*)d_in[7];
  const float* ffW    = (const float*)d_in[8];
  const float* ffb    = (const float*)d_in[9];
  const float* fw1    = (const float*)d_in[10];
  const float* fb1    = (const float*)d_in[11];
  const float* itW    = (const float*)d_in[12];
  const float* itb    = (const float*)d_in[13];

  char* ws = (char*)d_ws;   // total required: 88,936,064 bytes
  unsigned short* whbf  = (unsigned short*)(ws + 0);         // 1,048,576
  unsigned short* aw1   = (unsigned short*)(ws + 1048576);   //   262,144
  unsigned short* aw2   = (unsigned short*)(ws + 1310720);   //   262,144
  unsigned short* rwt   = (unsigned short*)(ws + 1572864);   //    36,864
  float*          hg    = (float*)(ws + 1609728);            //     9,600
  float*          trans = (float*)(ws + 1619328);            //     6,400
  float*          Pg    = (float*)(ws + 1625728);            // 1,048,576
  float*          Qg    = (float*)(ws + 2674304);            // 1,048,576
  float*          part  = (float*)(ws + 3722880);            // 1,032,192
  unsigned short* filtg = (unsigned short*)(ws + 4755072);   // 9,437,184
  unsigned short* memb  = (unsigned short*)(ws + 14454400);  // 67,108,864
  unsigned short* filtX = (unsigned short*)(ws + 81563264);  // 7,372,800

  k_prep <<<1129, 256, 0, stream>>>(e1, e2, rel, aW, ffW, ffb, itW, itb, word_h,
                                    whbf, aw1, aw2, rwt, hg, trans);
  k_pq   <<<512, 256, 0, stream>>>(whbf, aw1, aw2, Pg, Qg);
  k_fa   <<<4624, 256, 0, stream>>>(energy, rwt, Pg, Qg, arcb, memb,
                                    fw1, fb1, hg, filtX);
  k_tr   <<<256, 256, 0, stream>>>(filtX, filtg);
  k_conv <<<1024, 256, 0, stream>>>(filtg, memb, part);
  k_final<<<64, 256, 0, stream>>>(part, trans, (float*)d_out);
}

// Round 16
// 321.837 us; speedup vs baseline: 1.0359x; 1.0359x over previous
//
#include <hip/hip_runtime.h>
#include <stdint.h>

// Problem constants
// B=8, R=40, L=128, IN=256, WDIM=512, DREL=15, F=200 (pad 256), HID=300

#define LK(x) ((x) > 0.f ? (x) : 0.01f*(x))

typedef __attribute__((ext_vector_type(8))) short s16x8;
typedef __attribute__((ext_vector_type(4))) float f32x4;
typedef unsigned long long ull;

__device__ __forceinline__ unsigned short f2bf(float f) {
  union { float f; unsigned int u; } v; v.f = f;
  unsigned int u = v.u;
  return (unsigned short)((u + 0x7FFFu + ((u >> 16) & 1u)) >> 16);
}

// HW packed f32->bf16 (RNE, matches f2bf for normal floats): low16=lo, high16=hi
__device__ __forceinline__ unsigned cvtpk(float lo, float hi) {
  unsigned r;
  asm("v_cvt_pk_bf16_f32 %0, %1, %2" : "=v"(r) : "v"(lo), "v"(hi));
  return r;
}

__device__ __forceinline__ void gload_lds16(const void* g, void* l) {
  __builtin_amdgcn_global_load_lds(
      (const __attribute__((address_space(1))) unsigned int*)g,
      (__attribute__((address_space(3))) unsigned int*)l, 16, 0, 0);
}

// ---------------- Kernel A: small preps --------------------------------
// bid <600: h dots (wave-per-output); 600..999: trans dots; 1000..1063:
// word_h->bf16; 1064..1127: arc_W->bf16 (paired cvt_pk); 1128: RW^T.
__global__ __launch_bounds__(256) void k_prep(
    const float* __restrict__ e1, const float* __restrict__ e2,
    const float* __restrict__ rel, const float* __restrict__ aW,
    const float* __restrict__ ffW, const float* __restrict__ ffb,
    const float* __restrict__ itW, const float* __restrict__ itb,
    const float* __restrict__ wh,
    unsigned short* __restrict__ whbf, unsigned short* __restrict__ aw1,
    unsigned short* __restrict__ aw2, unsigned short* __restrict__ rwt,
    float* __restrict__ hg, float* __restrict__ trans)
{
  int bid = blockIdx.x, t = threadIdx.x;
  if (bid < 1000) {
    int wv = t >> 6, l = t & 63;
    bool ish = bid < 600;
    int idx = ish ? bid*4 + wv : (bid - 600)*4 + wv;
    int ob = ish ? 300 : 200;
    int b = idx / ob, o = idx - b*ob;
    const float* W = ish ? ffW : itW;
    const float* bias = ish ? ffb : itb;
    const float4* wr = (const float4*)(W + (size_t)o*1024) + l*4;
    const float* inb = (l < 32) ? (e1 + b*512 + l*16)
                                : (e2 + b*512 + (l - 32)*16);
    float s = 0.f;
#pragma unroll
    for (int q = 0; q < 4; ++q) {
      float4 w = wr[q];
      float4 v = *(const float4*)(inb + q*4);
      s += w.x*v.x + w.y*v.y + w.z*v.z + w.w*v.w;
    }
#pragma unroll
    for (int sh = 1; sh < 64; sh <<= 1)
      s += __shfl_xor(s, sh);
    if (l == 0) {
      float r = LK(s + bias[o]);
      if (ish) hg[b*300 + o] = r; else trans[b*200 + o] = r;
    }
  } else if (bid < 1064) {
    int id0 = (bid - 1000)*256 + t;
    for (int v = id0; v < 131072; v += 64*256) {
      float4 x = ((const float4*)wh)[v];
      unsigned lo  = cvtpk(x.x, x.y);
      unsigned hi2 = cvtpk(x.z, x.w);
      *(ull*)(whbf + (size_t)v*4) = (ull)lo | ((ull)hi2 << 32);
    }
  } else if (bid < 1128) {
    int id0 = (bid - 1064)*256 + t;
    for (int p = id0; p < 65536; p += 64*256) {
      int e = p*2;
      int o = e >> 9, k = e & 511;          // k even <= 510, pair in-row
      const float* ra = aW + (size_t)o*1039 + k;
      *(unsigned*)(aw1 + e) = cvtpk(ra[0], ra[1]);
      const float* rb = aW + (size_t)o*1039 + 512 + k;
      *(unsigned*)(aw2 + e) = cvtpk(rb[0], rb[1]);
    }
  } else {
    int o = t;
    for (int r = 0; r < 40; ++r) {
      float s = 0.f;
      for (int d = 0; d < 15; ++d) s += rel[r*15 + d] * aW[(size_t)o*1039 + 1024 + d];
      rwt[o*72 + r] = f2bf(s);
    }
    for (int r = 40; r < 72; ++r) rwt[o*72 + r] = 0;
  }
}

// ---------------- Kernel B: P/Q GEMMs (MFMA) ---------------------------
__global__ __launch_bounds__(256) void k_pq(
    const unsigned short* __restrict__ whbf,
    const unsigned short* __restrict__ aw1,
    const unsigned short* __restrict__ aw2,
    float* __restrict__ Pg, float* __restrict__ Qg)
{
  int bid = blockIdx.x, t = threadIdx.x;
  int g = bid >> 8;
  int wv = t >> 6, l = t & 63, lm = l & 15, hi = l >> 4;
  int tile = (bid & 255)*4 + wv;
  int ot = tile & 15, nt = tile >> 4;
  const unsigned short* A = g ? aw2 : aw1;
  float* out = g ? Qg : Pg;
  int orow = ot*16 + lm, n = nt*16 + lm;
  f32x4 acc = {0.f, 0.f, 0.f, 0.f};
  const unsigned short* ap = A + (size_t)orow*512 + hi*8;
  const unsigned short* bp = whbf + (size_t)n*512 + hi*8;
#pragma unroll
  for (int kk = 0; kk < 16; ++kk) {
    s16x8 af = *(const s16x8*)(ap + kk*32);
    s16x8 bf = *(const s16x8*)(bp + kk*32);
    acc = __builtin_amdgcn_mfma_f32_16x16x32_bf16(bf, af, acc, 0, 0, 0);
  }
  int nb = nt*16 + hi*4, o = ot*16 + lm;
#pragma unroll
  for (int r = 0; r < 4; ++r)
    out[(size_t)(nb + r)*256 + o] = acc[r];
}

// ---------------- Fused kernel: arc (blocks 0..1023) + filt (1024..8223)
// All f32->bf16 conversion via v_cvt_pk_bf16_f32 pairs (halves the VALU
// chains that serialize against the memory stream).
__global__ __launch_bounds__(256) void k_fa(
    const float* __restrict__ energy,
    const unsigned short* __restrict__ rwt,
    const float* __restrict__ Pg, const float* __restrict__ Qg,
    const float* __restrict__ arcb, unsigned short* __restrict__ memb,
    const float* __restrict__ fw1, const float* __restrict__ fb1,
    const float* __restrict__ hg, unsigned short* __restrict__ filtX)
{
  __shared__ __align__(16) char sm[21504];
  int bid = blockIdx.x, t = threadIdx.x;
  if (bid < 1024) {
    // ---------------- arc body ----------------
    unsigned short* Et = (unsigned short*)sm;        // 18,432 B
    float* mpart = (float*)(sm + 18432);             //  1,024 B
    float* qlds  = (float*)(sm + 19456);             //  1,024 B
    float* blds  = (float*)(sm + 20480);             //  1,024 B
    int b = bid >> 7, i = bid & 127;
    int jj = t & 127, half = t >> 7;
    float macc = 0.f;
    for (int rr = 0; rr < 20; rr += 2) {
      int r = half*20 + rr;                           // even -> 4-aligned
      float e0 = fmaxf(energy[(((size_t)b*40 + r  )*128 + i)*128 + jj], 0.f);
      float e1 = fmaxf(energy[(((size_t)b*40 + r+1)*128 + i)*128 + jj], 0.f);
      macc += e0;
      macc += e1;
      *(unsigned*)(Et + jj*72 + r) = cvtpk(e0, e1);
    }
    mpart[t] = macc;
    if (t < 128) {
#pragma unroll
      for (int r = 40; r < 72; ++r) Et[t*72 + r] = 0;
    }
    qlds[t] = Qg[((size_t)(b*128 + i))*256 + t];
    blds[t] = arcb[t];
    __syncthreads();

    int wv = t >> 6, l = t & 63, lm = l & 15, hi = l >> 4;
    unsigned short* mout = memb + ((size_t)(b*128 + i))*128*256;
    for (int otl = 0; otl < 4; ++otl) {
      int ocb = (wv*4 + otl)*16;
      const unsigned short* rp = rwt + (ocb + lm)*72 + hi*8;
      s16x8 rw0 = *(const s16x8*)rp;
      s16x8 rw1 = *(const s16x8*)(rp + 32);
      int oc0 = ocb + hi*4;
      float4 q4 = *(const float4*)&qlds[oc0];
      float4 b4 = *(const float4*)&blds[oc0];
      for (int jt = 0; jt < 8; ++jt) {
        const unsigned short* ep = &Et[(jt*16 + lm)*72 + hi*8];
        s16x8 et0 = *(const s16x8*)ep;
        s16x8 et1 = *(const s16x8*)(ep + 32);
        f32x4 acc = {0.f,0.f,0.f,0.f};
        acc = __builtin_amdgcn_mfma_f32_16x16x32_bf16(rw0, et0, acc, 0, 0, 0);
        acc = __builtin_amdgcn_mfma_f32_16x16x32_bf16(rw1, et1, acc, 0, 0, 0);
        int j = jt*16 + lm;
        float m = mpart[j] + mpart[128 + j];
        float4 p4 = *(const float4*)&Pg[((size_t)(b*128 + j))*256 + oc0];
        float vv0 = LK(acc[0] + m*(p4.x + q4.x) + b4.x);
        float vv1 = LK(acc[1] + m*(p4.y + q4.y) + b4.y);
        float vv2 = LK(acc[2] + m*(p4.z + q4.z) + b4.z);
        float vv3 = LK(acc[3] + m*(p4.w + q4.w) + b4.w);
        unsigned p0 = cvtpk(vv0, vv1), p1 = cvtpk(vv2, vv3);
        *(ull*)(mout + (size_t)j*256 + oc0) = (ull)p0 | ((ull)p1 << 32);
      }
    }
  } else {
    // ---------------- filt body ----------------
    unsigned short* Bbuf = (unsigned short*)sm;      // 10,240 B
    int r0 = (bid - 1024)*64;
    for (int idx = t; idx < 640; idx += 256) {
      int n = idx / 40, kc = idx - (idx/40)*40;
      unsigned w[4];
#pragma unroll
      for (int j = 0; j < 8; j += 2) {
        int k = kc*8 + j;
        float a = (n < 8 && k   < 300) ? hg[n*300 + k]     : 0.f;
        float b = (n < 8 && k+1 < 300) ? hg[n*300 + k + 1] : 0.f;
        w[j>>1] = cvtpk(a, b);
      }
      int byte = (n*640 + kc*16) ^ ((n & 7) << 4);
      *(uint4*)((char*)Bbuf + byte) = *(uint4*)w;
    }
    __syncthreads();
    int wv = t >> 6, l = t & 63, lm = l & 15, hi = l >> 4;
    const float* arow_p = fw1 + (size_t)((bid - 1024)*64 + wv*16 + lm)*300;
    f32x4 acc = {0.f, 0.f, 0.f, 0.f};
#pragma unroll
    for (int ks = 0; ks < 10; ++ks) {
      int k0 = ks*32 + hi*8;
      float av[8];
      if (k0 + 8 <= 300) {
        float4 v0 = *(const float4*)(arow_p + k0);
        float4 v1 = *(const float4*)(arow_p + k0 + 4);
        av[0]=v0.x; av[1]=v0.y; av[2]=v0.z; av[3]=v0.w;
        av[4]=v1.x; av[5]=v1.y; av[6]=v1.z; av[7]=v1.w;
      } else {
#pragma unroll
        for (int e = 0; e < 8; ++e) {
          int k = k0 + e;
          av[e] = (k < 300) ? arow_p[k] : 0.f;
        }
      }
      union { s16x8 v; unsigned u[4]; } af;
      af.u[0] = cvtpk(av[0], av[1]);
      af.u[1] = cvtpk(av[2], av[3]);
      af.u[2] = cvtpk(av[4], av[5]);
      af.u[3] = cvtpk(av[6], av[7]);
      int bbyte = (lm*640 + ks*64 + hi*16) ^ ((lm & 7) << 4);
      s16x8 bf = *(const s16x8*)((char*)Bbuf + bbyte);
      acc = __builtin_amdgcn_mfma_f32_16x16x32_bf16(af.v, bf, acc, 0, 0, 0);
    }
    if (lm < 8) {
#pragma unroll
      for (int r = 0; r < 4; ++r) {
        int wrow = (bid - 1024)*64 + wv*16 + hi*4 + r;
        float v = LK(acc[r] + fb1[wrow]);
        filtX[(size_t)wrow*8 + lm] = f2bf(v);
      }
    }
  }
}

// ---------------- Kernel C2: transpose filtX -> filtg ------------------
__global__ __launch_bounds__(256) void k_tr(
    const unsigned short* __restrict__ filtX,
    unsigned short* __restrict__ filtg)
{
  __shared__ unsigned short sh[8*2312];  // 36,992 B
  int bid = blockIdx.x, t = threadIdx.x;
  int dc = bid >> 5, fch = bid & 31;
  if (fch >= 25) {
    uint4 z = {0,0,0,0};
#pragma unroll
    for (int i = 0; i < 9; ++i) {
      int idx = t + i*256;
      int b = idx / 288, rem = idx - b*288;
      char* dst = (char*)filtg + ((size_t)(b*8+dc)*256 + fch*8)*576 + rem*16;
      *(uint4*)dst = z;
    }
    return;
  }
#pragma unroll
  for (int i = 0; i < 9; ++i) {
    int rr = t + i*256;
    int f_loc = rr / 288, e = rr - f_loc*288;
    int dl = e / 9, tap = e - dl*9;
    size_t wrow = (size_t)(fch*8 + f_loc)*2304 + dc*288 + e;
    uint4 v = *(const uint4*)((const char*)filtX + wrow*16);
    const unsigned short* pv = (const unsigned short*)&v;
    int base = f_loc*288 + tap*32 + dl;
#pragma unroll
    for (int b = 0; b < 8; ++b)
      sh[b*2312 + base] = pv[b];
  }
  __syncthreads();
#pragma unroll
  for (int i = 0; i < 9; ++i) {
    int idx = t + i*256;
    int b = idx / 288, rem = idx - b*288;
    uint4 v = *(const uint4*)((const char*)sh + b*4624 + rem*16);
    char* dst = (char*)filtg + ((size_t)(b*8+dc)*256 + fch*8)*576 + rem*16;
    *(uint4*)dst = v;
  }
}

// ---------------- Kernel D: conv + fused leaky/maxpool -----------------
// (r8 structure, unchanged; dur ~113 us from r9 probe)
__global__ __launch_bounds__(256, 2) void k_conv(
    const unsigned short* __restrict__ filtg,
    const unsigned short* __restrict__ memb,
    float* __restrict__ part)
{
  __shared__ __align__(16) char smem[50688];   // 6 rows x 528 x 16 B
  int t = threadIdx.x;
  int bid = (blockIdx.x & 7)*128 + (blockIdx.x >> 3);
  int yq = bid & 31;
  int tmp = bid >> 5;
  int fc = tmp & 3, b = tmp >> 2;
  int y0 = yq*4;
  int wv = t >> 6, l = t & 63, lm = l & 15, hi = l >> 4;
  int wx = wv & 1, wf = wv >> 1;

  f32x4 zero = {0.f,0.f,0.f,0.f};
  f32x4 acc[4][4][2];
#pragma unroll
  for (int yb = 0; yb < 4; ++yb)
#pragma unroll
    for (int xt = 0; xt < 4; ++xt) { acc[yb][xt][0] = zero; acc[yb][xt][1] = zero; }

  const char* fb0 = (const char*)filtg +
      ((size_t)(b*8)*256 + fc*64 + wf*32 + lm)*576 + hi*16;

  for (int dc = 0; dc < 8; ++dc) {
    s16x8 freg[2][9];
    const char* fdc = fb0 + (size_t)dc*(256*576);
#pragma unroll
    for (int ft = 0; ft < 2; ++ft)
#pragma unroll
      for (int tap = 0; tap < 9; ++tap)
        freg[ft][tap] = *(const s16x8*)(fdc + ft*(16*576) + tap*64);
    for (int c = wv; c < 50; c += 4) {
      int id = c*64 + l;
      if (id < 3168) {
        int ky = id / 528;
        int rem = id - ky*528;
        int x = rem >> 2, s = rem & 3;
        int cs = s ^ ((x >> 1) & 3);
        int xs = (x < 128) ? x : 127;
        int row = y0 + ky; if (row > 127) row = 127;
        const char* ms = (const char*)memb +
            (((((size_t)(b*128 + row))*128 + xs)*256) + dc*32 + cs*8)*2;
        gload_lds16(ms, smem + c*1024);
      }
    }
    __syncthreads();
#pragma unroll
    for (int r = 0; r < 6; ++r) {
#pragma unroll
      for (int kx = 0; kx < 3; ++kx) {
#pragma unroll
        for (int xt = 0; xt < 4; ++xt) {
          int x = wx*64 + xt*16 + lm + kx;
          int slot = hi ^ ((x >> 1) & 3);
          s16x8 af = *(const s16x8*)(smem + ((r*132 + x)*4 + slot)*16);
#pragma unroll
          for (int yb = 0; yb < 4; ++yb) {
            const int ky = r - yb;
            if (ky >= 0 && ky <= 2) {
              acc[yb][xt][0] = __builtin_amdgcn_mfma_f32_16x16x32_bf16(af, freg[0][ky*3+kx], acc[yb][xt][0], 0,0,0);
              acc[yb][xt][1] = __builtin_amdgcn_mfma_f32_16x16x32_bf16(af, freg[1][ky*3+kx], acc[yb][xt][1], 0,0,0);
            }
          }
        }
      }
    }
    __syncthreads();
  }

  float pm[4][2];
#pragma unroll
  for (int yb = 0; yb < 4; ++yb) { pm[yb][0] = -3.4e38f; pm[yb][1] = -3.4e38f; }
#pragma unroll
  for (int yb = 0; yb < 4; ++yb)
#pragma unroll
    for (int xt = 0; xt < 4; ++xt) {
      int xb = wx*64 + xt*16 + hi*4;
#pragma unroll
      for (int r = 0; r < 4; ++r) {
        if (xb + r < 126) {
          pm[yb][0] = fmaxf(pm[yb][0], acc[yb][xt][0][r]);
          pm[yb][1] = fmaxf(pm[yb][1], acc[yb][xt][1][r]);
        }
      }
    }
#pragma unroll
  for (int yb = 0; yb < 4; ++yb)
#pragma unroll
    for (int ft = 0; ft < 2; ++ft) {
      pm[yb][ft] = fmaxf(pm[yb][ft], __shfl_xor(pm[yb][ft], 16));
      pm[yb][ft] = fmaxf(pm[yb][ft], __shfl_xor(pm[yb][ft], 32));
    }
  float* red = (float*)smem;
  if (l < 16) {
#pragma unroll
    for (int yb = 0; yb < 4; ++yb)
#pragma unroll
      for (int ft = 0; ft < 2; ++ft)
        red[(yb*4 + wf*2 + wx)*32 + ft*16 + lm] = pm[yb][ft];
  }
  __syncthreads();
  {
    int yb = t >> 6, tt = t & 63;
    int wfi = tt >> 5, fi = tt & 31;
    if (y0 + yb < 126) {
      float v = fmaxf(red[(yb*4 + wfi*2 + 0)*32 + fi], red[(yb*4 + wfi*2 + 1)*32 + fi]);
      v = LK(v);
      part[((size_t)(b*126 + y0 + yb))*256 + fc*64 + tt] = v;
    }
  }
}

// ---------------- Final: reduce over y, add transformed ----------------
__global__ __launch_bounds__(256) void k_final(
    const float* __restrict__ part, const float* __restrict__ trans,
    float* __restrict__ out)
{
  int bid = blockIdx.x, t = threadIdx.x;
  int b = bid >> 3, fg = bid & 7;
  int f = fg*32 + (t >> 3), ys = t & 7;
  float m = -3.4e38f;
  for (int yy = ys; yy < 126; yy += 8)
    m = fmaxf(m, part[((size_t)(b*126 + yy))*256 + f]);
  m = fmaxf(m, __shfl_xor(m, 1));
  m = fmaxf(m, __shfl_xor(m, 2));
  m = fmaxf(m, __shfl_xor(m, 4));
  if (ys == 0 && f < 200)
    out[b*200 + f] = trans[b*200 + f] + m;
}

extern "C" void kernel_launch(void* const* d_in, const int* in_sizes, int n_in,
                              void* d_out, int out_size, void* d_ws, size_t ws_size,
                              hipStream_t stream)
{
  (void)in_sizes; (void)n_in; (void)out_size; (void)ws_size;
  const float* energy = (const float*)d_in[0];
  const float* word_h = (const float*)d_in[1];
  const float* e1     = (const float*)d_in[2];
  const float* e2     = (const float*)d_in[3];
  // d_in[4] sent_len unused
  const float* rel    = (const float*)d_in[5];
  const float* aW     = (const float*)d_in[6];
  const float* arcb   = (const float*)d_in[7];
  const float* ffW    = (const float*)d_in[8];
  const float* ffb    = (const float*)d_in[9];
  const float* fw1    = (const float*)d_in[10];
  const float* fb1    = (const float*)d_in[11];
  const float* itW    = (const float*)d_in[12];
  const float* itb    = (const float*)d_in[13];

  char* ws = (char*)d_ws;   // total required: 88,936,064 bytes
  unsigned short* whbf  = (unsigned short*)(ws + 0);         // 1,048,576
  unsigned short* aw1   = (unsigned short*)(ws + 1048576);   //   262,144
  unsigned short* aw2   = (unsigned short*)(ws + 1310720);   //   262,144
  unsigned short* rwt   = (unsigned short*)(ws + 1572864);   //    36,864
  float*          hg    = (float*)(ws + 1609728);            //     9,600
  float*          trans = (float*)(ws + 1619328);            //     6,400
  float*          Pg    = (float*)(ws + 1625728);            // 1,048,576
  float*          Qg    = (float*)(ws + 2674304);            // 1,048,576
  float*          part  = (float*)(ws + 3722880);            // 1,032,192
  unsigned short* filtg = (unsigned short*)(ws + 4755072);   // 9,437,184
  unsigned short* memb  = (unsigned short*)(ws + 14454400);  // 67,108,864
  unsigned short* filtX = (unsigned short*)(ws + 81563264);  // 7,372,800

  k_prep <<<1129, 256, 0, stream>>>(e1, e2, rel, aW, ffW, ffb, itW, itb, word_h,
                                    whbf, aw1, aw2, rwt, hg, trans);
  k_pq   <<<512, 256, 0, stream>>>(whbf, aw1, aw2, Pg, Qg);
  k_fa   <<<8224, 256, 0, stream>>>(energy, rwt, Pg, Qg, arcb, memb,
                                    fw1, fb1, hg, filtX);
  k_tr   <<<256, 256, 0, stream>>>(filtX, filtg);
  k_conv <<<1024, 256, 0, stream>>>(filtg, memb, part);
  k_final<<<64, 256, 0, stream>>>(part, trans, (float*)d_out);
}